// Round 1
// baseline (1253.700 us; speedup 1.0000x reference)
//
#include <hip/hip_runtime.h>
#include <math.h>

// Problem constants
#define BB 2
#define NN 512
#define CC 256
#define HH 256
#define WW 256
#define DIN 12544    // C * 7 * 7
#define OUT1 1024
#define NCLS 11      // NUM_CLASSES + 1
#define NROI 1024    // B * N

// ---------------------------------------------------------------------------
// NCHW -> NHWC transpose: per batch, transpose [C=256][HW=65536]
// ---------------------------------------------------------------------------
__global__ __launch_bounds__(256) void transpose_chw_hwc(
    const float* __restrict__ in, float* __restrict__ out) {
  __shared__ float tile[32][33];
  int b   = blockIdx.z;
  int hw0 = blockIdx.x * 32;
  int c0  = blockIdx.y * 32;
  int tx = threadIdx.x, ty = threadIdx.y;
#pragma unroll
  for (int j = 0; j < 4; ++j) {
    int c = c0 + ty + j * 8;
    tile[ty + j * 8][tx] = in[((size_t)b * CC + c) * (HH * WW) + hw0 + tx];
  }
  __syncthreads();
#pragma unroll
  for (int j = 0; j < 4; ++j) {
    int hw = hw0 + ty + j * 8;
    out[((size_t)b * (HH * WW) + hw) * CC + c0 + tx] = tile[tx][ty + j * 8];
  }
}

// ---------------------------------------------------------------------------
// Bilinear weight setup (matches reference semantics exactly)
// ---------------------------------------------------------------------------
__device__ inline void bilin(float gy, float gx, int& y0, int& x0, int& y1,
                             int& x1, float& w00, float& w01, float& w10,
                             float& w11) {
  float valid = (gy > -1.f && gy < 256.f && gx > -1.f && gx < 256.f) ? 0.25f : 0.f;
  float y = fminf(fmaxf(gy, 0.f), 255.f);
  float x = fminf(fmaxf(gx, 0.f), 255.f);
  float yf = floorf(y), xf = floorf(x);
  y0 = (int)yf; x0 = (int)xf;
  y1 = min(y0 + 1, 255); x1 = min(x0 + 1, 255);
  float ly = y - yf, lx = x - xf, hy = 1.f - ly, hx = 1.f - lx;
  w00 = hy * hx * valid; w01 = hy * lx * valid;
  w10 = ly * hx * valid; w11 = ly * lx * valid;
}

// ---------------------------------------------------------------------------
// ROI align rotated, NHWC input (coalesced). pooled[roi][bin*256 + c]
// One block per ROI; wave w handles bins w, w+4, ...; lane -> 4 channels.
// ---------------------------------------------------------------------------
__global__ __launch_bounds__(256) void roi_align_hwc(
    const float* __restrict__ fhwc, const float* __restrict__ props,
    float* __restrict__ pooled) {
  int roi = blockIdx.x;
  int b = roi / NN;
  const float* p = props + (size_t)roi * 5;
  float cx = p[0], cy = p[1], w = p[2], h = p[3], th = p[4];
  float sn = sinf(th), cs = cosf(th);
  int wave = threadIdx.x >> 6, lane = threadIdx.x & 63;
  int c4 = lane * 4;
  const float* fb = fhwc + (size_t)b * HH * WW * CC;
  float* outp = pooled + (size_t)roi * DIN;

  for (int bin = wave; bin < 49; bin += 4) {
    int py = bin / 7, px = bin % 7;
    float4 acc = make_float4(0.f, 0.f, 0.f, 0.f);
#pragma unroll
    for (int sy = 0; sy < 2; ++sy) {
#pragma unroll
      for (int sx = 0; sx < 2; ++sx) {
        float ys = -0.5f * h + (h / 7.0f) * ((float)py + ((float)sy + 0.5f) * 0.5f);
        float xs = -0.5f * w + (w / 7.0f) * ((float)px + ((float)sx + 0.5f) * 0.5f);
        float gx = cx + xs * cs - ys * sn;
        float gy = cy + xs * sn + ys * cs;
        int y0, x0, y1, x1; float w00, w01, w10, w11;
        bilin(gy, gx, y0, x0, y1, x1, w00, w01, w10, w11);
        float4 v00 = *(const float4*)(fb + ((size_t)y0 * WW + x0) * CC + c4);
        float4 v01 = *(const float4*)(fb + ((size_t)y0 * WW + x1) * CC + c4);
        float4 v10 = *(const float4*)(fb + ((size_t)y1 * WW + x0) * CC + c4);
        float4 v11 = *(const float4*)(fb + ((size_t)y1 * WW + x1) * CC + c4);
        acc.x += w00 * v00.x + w01 * v01.x + w10 * v10.x + w11 * v11.x;
        acc.y += w00 * v00.y + w01 * v01.y + w10 * v10.y + w11 * v11.y;
        acc.z += w00 * v00.z + w01 * v01.z + w10 * v10.z + w11 * v11.z;
        acc.w += w00 * v00.w + w01 * v01.w + w10 * v10.w + w11 * v11.w;
      }
    }
    *(float4*)(outp + bin * 256 + c4) = acc;
  }
}

// ---------------------------------------------------------------------------
// Fallback: ROI align directly from NCHW (uncoalesced but needs less ws)
// One block per ROI, one thread per channel.
// ---------------------------------------------------------------------------
__global__ __launch_bounds__(256) void roi_align_nchw(
    const float* __restrict__ feat, const float* __restrict__ props,
    float* __restrict__ pooled) {
  int roi = blockIdx.x;
  int b = roi / NN;
  int c = threadIdx.x;
  const float* p = props + (size_t)roi * 5;
  float cx = p[0], cy = p[1], w = p[2], h = p[3], th = p[4];
  float sn = sinf(th), cs = cosf(th);
  const float* fb = feat + ((size_t)b * CC + c) * (HH * WW);
  float* outp = pooled + (size_t)roi * DIN;

  for (int bin = 0; bin < 49; ++bin) {
    int py = bin / 7, px = bin % 7;
    float acc = 0.f;
#pragma unroll
    for (int sy = 0; sy < 2; ++sy) {
#pragma unroll
      for (int sx = 0; sx < 2; ++sx) {
        float ys = -0.5f * h + (h / 7.0f) * ((float)py + ((float)sy + 0.5f) * 0.5f);
        float xs = -0.5f * w + (w / 7.0f) * ((float)px + ((float)sx + 0.5f) * 0.5f);
        float gx = cx + xs * cs - ys * sn;
        float gy = cy + xs * sn + ys * cs;
        int y0, x0, y1, x1; float w00, w01, w10, w11;
        bilin(gy, gx, y0, x0, y1, x1, w00, w01, w10, w11);
        acc += w00 * fb[(size_t)y0 * WW + x0] + w01 * fb[(size_t)y0 * WW + x1] +
               w10 * fb[(size_t)y1 * WW + x0] + w11 * fb[(size_t)y1 * WW + x1];
      }
    }
    outp[bin * 256 + c] = acc;
  }
}

// ---------------------------------------------------------------------------
// fp32 tiled GEMM: C = relu?(A @ Bw + bias). A is MxK row-major (K-index is
// k' = bin*256+c when PERM), Bw is KxN row-major (rows permuted when PERM).
// 64x64 tile, 256 threads, 4x4 per thread, BK=16.
// ---------------------------------------------------------------------------
template <bool PERM, bool RELU>
__global__ __launch_bounds__(256) void gemm_tiled(
    const float* __restrict__ A, const float* __restrict__ Bw,
    const float* __restrict__ bias, float* __restrict__ Cm, int M, int N,
    int K) {
  __shared__ float As[16][64];
  __shared__ float Bs[16][64];
  int tid = threadIdx.x;
  int m0 = blockIdx.y * 64, n0 = blockIdx.x * 64;
  int ty = tid >> 4, tx = tid & 15;
  float acc[4][4] = {};
  int am = tid >> 2;        // 0..63 (row within tile)
  int ak = (tid & 3) * 4;   // 0,4,8,12
  int bk = tid >> 4;        // 0..15
  int bn = (tid & 15) * 4;  // 0..60

  for (int k0 = 0; k0 < K; k0 += 16) {
    float4 av = *(const float4*)(A + (size_t)(m0 + am) * K + k0 + ak);
    int kk = k0 + bk;
    int brow = PERM ? ((kk & 255) * 49 + (kk >> 8)) : kk;
    float4 bv = *(const float4*)(Bw + (size_t)brow * N + n0 + bn);
    __syncthreads();  // previous iteration's reads complete before overwrite
    As[ak + 0][am] = av.x;
    As[ak + 1][am] = av.y;
    As[ak + 2][am] = av.z;
    As[ak + 3][am] = av.w;
    *(float4*)&Bs[bk][bn] = bv;
    __syncthreads();
#pragma unroll
    for (int q = 0; q < 16; ++q) {
      float a4[4], b4[4];
      *(float4*)a4 = *(const float4*)&As[q][ty * 4];
      *(float4*)b4 = *(const float4*)&Bs[q][tx * 4];
#pragma unroll
      for (int i = 0; i < 4; ++i)
#pragma unroll
        for (int j = 0; j < 4; ++j) acc[i][j] += a4[i] * b4[j];
    }
  }
  float bsv[4];
  *(float4*)bsv = *(const float4*)(bias + n0 + tx * 4);
#pragma unroll
  for (int i = 0; i < 4; ++i) {
    int row = m0 + ty * 4 + i;
    float r[4];
#pragma unroll
    for (int j = 0; j < 4; ++j) {
      float v = acc[i][j] + bsv[j];
      r[j] = RELU ? fmaxf(v, 0.f) : v;
    }
    *(float4*)(Cm + (size_t)row * N + n0 + tx * 4) = *(float4*)r;
  }
}

// ---------------------------------------------------------------------------
// Head: cls = x@Wcls + bcls ; reg = x@Wreg + breg ; box decode.
// One block per (b,n) row. Output: boxes at out[0:5120], cls at out[5120:].
// ---------------------------------------------------------------------------
__global__ __launch_bounds__(256) void head_kernel(
    const float* __restrict__ X, const float* __restrict__ Wcls,
    const float* __restrict__ bcls, const float* __restrict__ Wreg,
    const float* __restrict__ breg, const float* __restrict__ props,
    float* __restrict__ out) {
  __shared__ float xrow[1024];
  __shared__ float partial[16][17];
  __shared__ float res[16];
  int row = blockIdx.x;
  int tid = threadIdx.x;
  const float* xp = X + (size_t)row * 1024;
  *(float4*)&xrow[tid * 4] = *(const float4*)(xp + tid * 4);
  __syncthreads();
  int col = tid & 15, slice = tid >> 4;
  float s = 0.f;
  if (col < NCLS) {
    for (int k = slice * 64; k < slice * 64 + 64; ++k)
      s += xrow[k] * Wcls[(size_t)k * NCLS + col];
  } else {
    int rc = col - NCLS;
    for (int k = slice * 64; k < slice * 64 + 64; ++k)
      s += xrow[k] * Wreg[(size_t)k * 5 + rc];
  }
  partial[slice][col] = s;
  __syncthreads();
  if (tid < 16) {
    float t = 0.f;
    for (int sl = 0; sl < 16; ++sl) t += partial[sl][tid];
    t += (tid < NCLS) ? bcls[tid] : breg[tid - NCLS];
    res[tid] = t;
  }
  __syncthreads();
  if (tid < NCLS) out[5120 + (size_t)row * NCLS + tid] = res[tid];
  if (tid == 0) {
    const float* p = props + (size_t)row * 5;
    float p0 = p[0] * 4.f, p1 = p[1] * 4.f, p2 = p[2] * 4.f, p3 = p[3] * 4.f,
          p4 = p[4];
    float r0 = res[11], r1 = res[12], r2 = res[13], r3 = res[14], r4 = res[15];
    const float V = 4.135166556742356f;  // |log(16/1000)|
    float bx = p2 * r0 + p0;
    float by = p3 * r1 + p1;
    float bw = p2 * expf(fminf(fmaxf(r2, -V), V));
    float bh = p3 * expf(fminf(fmaxf(r3, -V), V));
    const float PI = 3.14159265358979323846f;
    float a = p4 + r4;
    float m = fmodf(a + PI * 0.5f, PI);
    if (m < 0.f) m += PI;
    float ba = m - PI * 0.5f;
    float* bo = out + (size_t)row * 5;
    bo[0] = bx; bo[1] = by; bo[2] = bw; bo[3] = bh; bo[4] = ba;
  }
}

// ---------------------------------------------------------------------------
extern "C" void kernel_launch(void* const* d_in, const int* in_sizes, int n_in,
                              void* d_out, int out_size, void* d_ws,
                              size_t ws_size, hipStream_t stream) {
  const float* feat  = (const float*)d_in[0];
  const float* props = (const float*)d_in[1];
  const float* W1    = (const float*)d_in[2];
  const float* b1    = (const float*)d_in[3];
  const float* W2    = (const float*)d_in[4];
  const float* b2    = (const float*)d_in[5];
  const float* Wcls  = (const float*)d_in[6];
  const float* bcls  = (const float*)d_in[7];
  const float* Wreg  = (const float*)d_in[8];
  const float* breg  = (const float*)d_in[9];
  float* out = (float*)d_out;

  float* pooled = (float*)d_ws;                       // 1024 x 12544
  float* x1 = pooled + (size_t)NROI * DIN;            // 1024 x 1024
  float* x2 = x1 + (size_t)NROI * OUT1;               // 1024 x 1024
  float* fhwc = x2 + (size_t)NROI * OUT1;             // 2 x 256 x 256 x 256

  size_t need_full =
      ((size_t)NROI * DIN + 2 * (size_t)NROI * OUT1 + (size_t)BB * CC * HH * WW) *
      sizeof(float);

  if (ws_size >= need_full) {
    dim3 g(HH * WW / 32, CC / 32, BB);
    dim3 blk(32, 8);
    transpose_chw_hwc<<<g, blk, 0, stream>>>(feat, fhwc);
    roi_align_hwc<<<NROI, 256, 0, stream>>>(fhwc, props, pooled);
  } else {
    roi_align_nchw<<<NROI, 256, 0, stream>>>(feat, props, pooled);
  }

  gemm_tiled<true, true><<<dim3(16, 16), 256, 0, stream>>>(
      pooled, W1, b1, x1, NROI, OUT1, DIN);
  gemm_tiled<false, true><<<dim3(16, 16), 256, 0, stream>>>(
      x1, W2, b2, x2, NROI, OUT1, OUT1);
  head_kernel<<<NROI, 256, 0, stream>>>(x2, Wcls, bcls, Wreg, breg, props, out);
}

// Round 2
// 422.088 us; speedup vs baseline: 2.9702x; 2.9702x over previous
//
#include <hip/hip_runtime.h>
#include <math.h>
#include <stdint.h>

#define BB 2
#define NN 512
#define CC 256
#define HH 256
#define WW 256
#define DIN 12544    // C * 7 * 7
#define OUT1 1024
#define NCLS 11      // NUM_CLASSES + 1
#define NROI 1024    // B * N

typedef short bf16x8 __attribute__((ext_vector_type(8)));
typedef float f32x4 __attribute__((ext_vector_type(4)));

__device__ inline unsigned short f2bf(float f) {
  unsigned int u = __float_as_uint(f);
  u += 0x7FFF + ((u >> 16) & 1);  // round-to-nearest-even
  return (unsigned short)(u >> 16);
}
__device__ inline float bf2f(unsigned short h) {
  return __uint_as_float(((unsigned int)h) << 16);
}
__device__ inline float4 ld_bf4(const unsigned short* p) {
  ushort4 r = *(const ushort4*)p;
  return make_float4(bf2f(r.x), bf2f(r.y), bf2f(r.z), bf2f(r.w));
}

// async global->LDS, 16B per lane; lds ptr must be wave-uniform
__device__ inline void gll16(const void* g, void* l) {
  __builtin_amdgcn_global_load_lds(
      reinterpret_cast<const __attribute__((address_space(1))) void*>(
          reinterpret_cast<uintptr_t>(g)),
      reinterpret_cast<__attribute__((address_space(3))) void*>(
          (unsigned int)reinterpret_cast<uintptr_t>(l)),
      16, 0, 0);
}

// ---------------------------------------------------------------------------
// NCHW fp32 -> NHWC bf16. Tile 64hw x 64c via LDS (pad 65, scalar LDS ops:
// both phases land 2-way bank aliasing = free per m136).
// ---------------------------------------------------------------------------
__global__ __launch_bounds__(256) void transpose_to_hwc_bf16(
    const float* __restrict__ in, unsigned short* __restrict__ out) {
  __shared__ float tile[64][65];
  int b = blockIdx.z;
  int hw0 = blockIdx.x * 64;
  int c0 = blockIdx.y * 64;
  int tid = threadIdx.x;
  int hi = tid >> 4, lo = tid & 15;
#pragma unroll
  for (int pass = 0; pass < 4; ++pass) {
    int cl = hi + pass * 16;
    float4 v = *(const float4*)(in + ((size_t)b * CC + c0 + cl) * (HH * WW) +
                                hw0 + lo * 4);
    tile[lo * 4 + 0][cl] = v.x;
    tile[lo * 4 + 1][cl] = v.y;
    tile[lo * 4 + 2][cl] = v.z;
    tile[lo * 4 + 3][cl] = v.w;
  }
  __syncthreads();
#pragma unroll
  for (int pass = 0; pass < 4; ++pass) {
    int hwl = hi + pass * 16;
    int cc = lo * 4;
    ushort4 o;
    o.x = f2bf(tile[hwl][cc + 0]);
    o.y = f2bf(tile[hwl][cc + 1]);
    o.z = f2bf(tile[hwl][cc + 2]);
    o.w = f2bf(tile[hwl][cc + 3]);
    *(ushort4*)(out + ((size_t)b * (HH * WW) + hw0 + hwl) * CC + c0 + cc) = o;
  }
}

// ---------------------------------------------------------------------------
__device__ inline void bilin(float gy, float gx, int& y0, int& x0, int& y1,
                             int& x1, float& w00, float& w01, float& w10,
                             float& w11) {
  float valid = (gy > -1.f && gy < 256.f && gx > -1.f && gx < 256.f) ? 0.25f : 0.f;
  float y = fminf(fmaxf(gy, 0.f), 255.f);
  float x = fminf(fmaxf(gx, 0.f), 255.f);
  float yf = floorf(y), xf = floorf(x);
  y0 = (int)yf; x0 = (int)xf;
  y1 = min(y0 + 1, 255); x1 = min(x0 + 1, 255);
  float ly = y - yf, lx = x - xf, hy = 1.f - ly, hx = 1.f - lx;
  w00 = hy * hx * valid; w01 = hy * lx * valid;
  w10 = ly * hx * valid; w11 = ly * lx * valid;
}

// ---------------------------------------------------------------------------
// ROI align rotated from NHWC bf16. pooled (bf16) layout [roi][bin*256 + c].
// ---------------------------------------------------------------------------
__global__ __launch_bounds__(256) void roi_align_hwc(
    const unsigned short* __restrict__ fhwc, const float* __restrict__ props,
    unsigned short* __restrict__ pooled) {
  int roi = blockIdx.x;
  int b = roi >> 9;
  const float* p = props + (size_t)roi * 5;
  float cx = p[0], cy = p[1], w = p[2], h = p[3], th = p[4];
  float sn = sinf(th), cs = cosf(th);
  int wave = threadIdx.x >> 6, lane = threadIdx.x & 63;
  int c4 = lane * 4;
  const unsigned short* fb = fhwc + (size_t)b * HH * WW * CC;
  unsigned short* outp = pooled + (size_t)roi * DIN;

  for (int bin = wave; bin < 49; bin += 4) {
    int py = bin / 7, px = bin - py * 7;
    float a0 = 0.f, a1 = 0.f, a2 = 0.f, a3 = 0.f;
#pragma unroll
    for (int sy = 0; sy < 2; ++sy) {
#pragma unroll
      for (int sx = 0; sx < 2; ++sx) {
        float ys = -0.5f * h + (h / 7.0f) * ((float)py + ((float)sy + 0.5f) * 0.5f);
        float xs = -0.5f * w + (w / 7.0f) * ((float)px + ((float)sx + 0.5f) * 0.5f);
        float gx = cx + xs * cs - ys * sn;
        float gy = cy + xs * sn + ys * cs;
        int y0, x0, y1, x1; float w00, w01, w10, w11;
        bilin(gy, gx, y0, x0, y1, x1, w00, w01, w10, w11);
        float4 v00 = ld_bf4(fb + ((size_t)(y0 * WW + x0)) * CC + c4);
        float4 v01 = ld_bf4(fb + ((size_t)(y0 * WW + x1)) * CC + c4);
        float4 v10 = ld_bf4(fb + ((size_t)(y1 * WW + x0)) * CC + c4);
        float4 v11 = ld_bf4(fb + ((size_t)(y1 * WW + x1)) * CC + c4);
        a0 += w00 * v00.x + w01 * v01.x + w10 * v10.x + w11 * v11.x;
        a1 += w00 * v00.y + w01 * v01.y + w10 * v10.y + w11 * v11.y;
        a2 += w00 * v00.z + w01 * v01.z + w10 * v10.z + w11 * v11.z;
        a3 += w00 * v00.w + w01 * v01.w + w10 * v10.w + w11 * v11.w;
      }
    }
    ushort4 o;
    o.x = f2bf(a0); o.y = f2bf(a1); o.z = f2bf(a2); o.w = f2bf(a3);
    *(ushort4*)(outp + bin * 256 + c4) = o;
  }
}

// Fallback: direct NCHW gather (small-ws path)
__global__ __launch_bounds__(256) void roi_align_nchw(
    const float* __restrict__ feat, const float* __restrict__ props,
    unsigned short* __restrict__ pooled) {
  int roi = blockIdx.x;
  int b = roi >> 9;
  int c = threadIdx.x;
  const float* p = props + (size_t)roi * 5;
  float cx = p[0], cy = p[1], w = p[2], h = p[3], th = p[4];
  float sn = sinf(th), cs = cosf(th);
  const float* fb = feat + ((size_t)b * CC + c) * (HH * WW);
  unsigned short* outp = pooled + (size_t)roi * DIN;
  for (int bin = 0; bin < 49; ++bin) {
    int py = bin / 7, px = bin - py * 7;
    float acc = 0.f;
#pragma unroll
    for (int sy = 0; sy < 2; ++sy) {
#pragma unroll
      for (int sx = 0; sx < 2; ++sx) {
        float ys = -0.5f * h + (h / 7.0f) * ((float)py + ((float)sy + 0.5f) * 0.5f);
        float xs = -0.5f * w + (w / 7.0f) * ((float)px + ((float)sx + 0.5f) * 0.5f);
        float gx = cx + xs * cs - ys * sn;
        float gy = cy + xs * sn + ys * cs;
        int y0, x0, y1, x1; float w00, w01, w10, w11;
        bilin(gy, gx, y0, x0, y1, x1, w00, w01, w10, w11);
        acc += w00 * fb[(size_t)y0 * WW + x0] + w01 * fb[(size_t)y0 * WW + x1] +
               w10 * fb[(size_t)y1 * WW + x0] + w11 * fb[(size_t)y1 * WW + x1];
      }
    }
    outp[bin * 256 + c] = f2bf(acc);
  }
}

// ---------------------------------------------------------------------------
// Weight convert: out[n][k'] = bf16(in[perm(k')][n]); perm(k')=(k'&255)*49+(k'>>8)
// when PERM (matches pooled's k' = bin*256+c ordering). Tile 64x64 via LDS.
// ---------------------------------------------------------------------------
template <bool PERM>
__global__ __launch_bounds__(256) void cvt_w(const float* __restrict__ in,
                                             unsigned short* __restrict__ out,
                                             int N, int Kout) {
  __shared__ float tile[64][65];
  int k0 = blockIdx.x * 64, n0 = blockIdx.y * 64;
  int tid = threadIdx.x;
  int hi = tid >> 4, lo = tid & 15;
#pragma unroll
  for (int pass = 0; pass < 4; ++pass) {
    int ki = hi + pass * 16;
    int k = k0 + ki;
    int row = PERM ? ((k & 255) * 49 + (k >> 8)) : k;
    float4 v = *(const float4*)(in + (size_t)row * N + n0 + lo * 4);
    tile[ki][lo * 4 + 0] = v.x;
    tile[ki][lo * 4 + 1] = v.y;
    tile[ki][lo * 4 + 2] = v.z;
    tile[ki][lo * 4 + 3] = v.w;
  }
  __syncthreads();
#pragma unroll
  for (int pass = 0; pass < 4; ++pass) {
    int nl = hi + pass * 16;
    int kq = lo * 4;
    ushort4 o;
    o.x = f2bf(tile[kq + 0][nl]);
    o.y = f2bf(tile[kq + 1][nl]);
    o.z = f2bf(tile[kq + 2][nl]);
    o.w = f2bf(tile[kq + 3][nl]);
    *(ushort4*)(out + (size_t)(n0 + nl) * Kout + k0 + kq) = o;
  }
}

// ---------------------------------------------------------------------------
// MFMA GEMM, 128x128 tile, BK=32, split-K partials (fp32, no bias).
// A [M][K] bf16 row-major; Bw [N][K] bf16 row-major. part[z] = A·Bw^T slice.
// 4 waves, each 64x64 = 4x4 tiles of 16x16x32. m97 2-barrier structure.
// ---------------------------------------------------------------------------
__global__ __launch_bounds__(256) void gemm_mfma_128(
    const unsigned short* __restrict__ A, const unsigned short* __restrict__ Bw,
    float* __restrict__ part, int K, int Ks) {
  __shared__ short As[128 * 32];
  __shared__ short Bs[128 * 32];
  int tid = threadIdx.x;
  int w = tid >> 6, lane = tid & 63;
  int quad = lane >> 4, l16 = lane & 15;
  int m0 = blockIdx.y * 128, n0 = blockIdx.x * 128;
  int bz = blockIdx.z;
  int wm = w >> 1, wn = w & 1;

  const char* pA = (const char*)A +
      ((size_t)(m0 + 32 * w + (lane >> 2)) * K + (size_t)bz * Ks) * 2 +
      (lane & 3) * 16;
  const char* pB = (const char*)Bw +
      ((size_t)(n0 + 32 * w + (lane >> 2)) * K + (size_t)bz * Ks) * 2 +
      (lane & 3) * 16;
  short* la = &As[w * 1024];
  short* lb = &Bs[w * 1024];
  const size_t rstep = (size_t)K * 2 * 16;  // +16 rows

  f32x4 acc[4][4] = {};
  int aoff[4], boff[4];
#pragma unroll
  for (int t = 0; t < 4; ++t) {
    aoff[t] = (wm * 64 + t * 16 + l16) * 32 + quad * 8;
    boff[t] = (wn * 64 + t * 16 + l16) * 32 + quad * 8;
  }

  for (int kk = 0; kk < Ks; kk += 32) {
    __syncthreads();  // prior reads done before LDS overwrite
    gll16(pA, la);
    gll16(pA + rstep, la + 512);
    gll16(pB, lb);
    gll16(pB + rstep, lb + 512);
    pA += 64; pB += 64;
    __syncthreads();  // vmcnt(0) drained -> LDS valid
    bf16x8 af[4], bfr[4];
#pragma unroll
    for (int t = 0; t < 4; ++t) af[t] = *(const bf16x8*)&As[aoff[t]];
#pragma unroll
    for (int t = 0; t < 4; ++t) bfr[t] = *(const bf16x8*)&Bs[boff[t]];
#pragma unroll
    for (int mt = 0; mt < 4; ++mt)
#pragma unroll
      for (int nt = 0; nt < 4; ++nt)
        acc[mt][nt] = __builtin_amdgcn_mfma_f32_16x16x32_bf16(
            af[mt], bfr[nt], acc[mt][nt], 0, 0, 0);
  }

  float* pp = part + (size_t)bz * (OUT1 * NROI);
#pragma unroll
  for (int mt = 0; mt < 4; ++mt)
#pragma unroll
    for (int nt = 0; nt < 4; ++nt) {
      int col = n0 + wn * 64 + nt * 16 + l16;
#pragma unroll
      for (int r = 0; r < 4; ++r) {
        int row = m0 + wm * 64 + mt * 16 + quad * 4 + r;
        pp[(size_t)row * OUT1 + col] = acc[mt][nt][r];
      }
    }
}

// split-K reduce + bias + relu -> bf16
__global__ __launch_bounds__(256) void reduce_relu_bf16(
    const float* __restrict__ part, const float* __restrict__ bias,
    unsigned short* __restrict__ out) {
  int i = blockIdx.x * 256 + threadIdx.x;  // float4 index
  int base = i * 4;
  int col = base & (OUT1 - 1);
  const float4* p = (const float4*)part;
  float4 s0 = p[i];
  float4 s1 = p[i + 262144];
  float4 s2 = p[i + 524288];
  float4 s3 = p[i + 786432];
  float4 bv = *(const float4*)(bias + col);
  ushort4 o;
  o.x = f2bf(fmaxf(s0.x + s1.x + s2.x + s3.x + bv.x, 0.f));
  o.y = f2bf(fmaxf(s0.y + s1.y + s2.y + s3.y + bv.y, 0.f));
  o.z = f2bf(fmaxf(s0.z + s1.z + s2.z + s3.z + bv.z, 0.f));
  o.w = f2bf(fmaxf(s0.w + s1.w + s2.w + s3.w + bv.w, 0.f));
  *(ushort4*)(out + base) = o;
}

// ---------------------------------------------------------------------------
// MFMA GEMM, 64x64 tile, BK=64, fused bias+relu, fp32 out. A[M][K], Bw[N][K].
// ---------------------------------------------------------------------------
__global__ __launch_bounds__(256) void gemm_mfma_64_fused(
    const unsigned short* __restrict__ A, const unsigned short* __restrict__ Bw,
    const float* __restrict__ bias, float* __restrict__ C, int K) {
  __shared__ short As[64 * 64];
  __shared__ short Bs[64 * 64];
  int tid = threadIdx.x;
  int w = tid >> 6, lane = tid & 63;
  int quad = lane >> 4, l16 = lane & 15;
  int m0 = blockIdx.y * 64, n0 = blockIdx.x * 64;
  int wm = w >> 1, wn = w & 1;

  const char* pA = (const char*)A +
      (size_t)(m0 + 16 * w + (lane >> 3)) * K * 2 + (lane & 7) * 16;
  const char* pB = (const char*)Bw +
      (size_t)(n0 + 16 * w + (lane >> 3)) * K * 2 + (lane & 7) * 16;
  short* la = &As[w * 1024];
  short* lb = &Bs[w * 1024];
  const size_t rstep = (size_t)K * 2 * 8;  // +8 rows

  f32x4 acc[2][2] = {};
  int aoff[2], boff[2];
#pragma unroll
  for (int t = 0; t < 2; ++t) {
    aoff[t] = (wm * 32 + t * 16 + l16) * 64 + quad * 8;
    boff[t] = (wn * 32 + t * 16 + l16) * 64 + quad * 8;
  }

  for (int kk = 0; kk < K; kk += 64) {
    __syncthreads();
    gll16(pA, la);
    gll16(pA + rstep, la + 512);
    gll16(pB, lb);
    gll16(pB + rstep, lb + 512);
    pA += 128; pB += 128;
    __syncthreads();
#pragma unroll
    for (int ks = 0; ks < 2; ++ks) {
      bf16x8 af[2], bfr[2];
#pragma unroll
      for (int t = 0; t < 2; ++t) af[t] = *(const bf16x8*)&As[aoff[t] + ks * 32];
#pragma unroll
      for (int t = 0; t < 2; ++t) bfr[t] = *(const bf16x8*)&Bs[boff[t] + ks * 32];
#pragma unroll
      for (int mt = 0; mt < 2; ++mt)
#pragma unroll
        for (int nt = 0; nt < 2; ++nt)
          acc[mt][nt] = __builtin_amdgcn_mfma_f32_16x16x32_bf16(
              af[mt], bfr[nt], acc[mt][nt], 0, 0, 0);
    }
  }
#pragma unroll
  for (int mt = 0; mt < 2; ++mt)
#pragma unroll
    for (int nt = 0; nt < 2; ++nt) {
      int col = n0 + wn * 32 + nt * 16 + l16;
      float bv = bias[col];
#pragma unroll
      for (int r = 0; r < 4; ++r) {
        int row = m0 + wm * 32 + mt * 16 + quad * 4 + r;
        C[(size_t)row * OUT1 + col] = fmaxf(acc[mt][nt][r] + bv, 0.f);
      }
    }
}

// ---------------------------------------------------------------------------
// Head: cls/reg GEMV + box decode. x2 fp32 [1024][1024].
// ---------------------------------------------------------------------------
__global__ __launch_bounds__(256) void head_kernel(
    const float* __restrict__ X, const float* __restrict__ Wcls,
    const float* __restrict__ bcls, const float* __restrict__ Wreg,
    const float* __restrict__ breg, const float* __restrict__ props,
    float* __restrict__ out) {
  __shared__ float xrow[1024];
  __shared__ float partial[16][17];
  __shared__ float res[16];
  int row = blockIdx.x;
  int tid = threadIdx.x;
  const float* xp = X + (size_t)row * 1024;
  *(float4*)&xrow[tid * 4] = *(const float4*)(xp + tid * 4);
  __syncthreads();
  int col = tid & 15, slice = tid >> 4;
  float s = 0.f;
  if (col < NCLS) {
    for (int k = slice * 64; k < slice * 64 + 64; ++k)
      s += xrow[k] * Wcls[(size_t)k * NCLS + col];
  } else {
    int rc = col - NCLS;
    for (int k = slice * 64; k < slice * 64 + 64; ++k)
      s += xrow[k] * Wreg[(size_t)k * 5 + rc];
  }
  partial[slice][col] = s;
  __syncthreads();
  if (tid < 16) {
    float t = 0.f;
    for (int sl = 0; sl < 16; ++sl) t += partial[sl][tid];
    t += (tid < NCLS) ? bcls[tid] : breg[tid - NCLS];
    res[tid] = t;
  }
  __syncthreads();
  if (tid < NCLS) out[5120 + (size_t)row * NCLS + tid] = res[tid];
  if (tid == 0) {
    const float* p = props + (size_t)row * 5;
    float p0 = p[0] * 4.f, p1 = p[1] * 4.f, p2 = p[2] * 4.f, p3 = p[3] * 4.f,
          p4 = p[4];
    float r0 = res[11], r1 = res[12], r2 = res[13], r3 = res[14], r4 = res[15];
    const float V = 4.135166556742356f;  // |log(16/1000)|
    float bx = p2 * r0 + p0;
    float by = p3 * r1 + p1;
    float bw = p2 * expf(fminf(fmaxf(r2, -V), V));
    float bh = p3 * expf(fminf(fmaxf(r3, -V), V));
    const float PI = 3.14159265358979323846f;
    float a = p4 + r4;
    float m = fmodf(a + PI * 0.5f, PI);
    if (m < 0.f) m += PI;
    float ba = m - PI * 0.5f;
    float* bo = out + (size_t)row * 5;
    bo[0] = bx; bo[1] = by; bo[2] = bw; bo[3] = bh; bo[4] = ba;
  }
}

// ---------------------------------------------------------------------------
extern "C" void kernel_launch(void* const* d_in, const int* in_sizes, int n_in,
                              void* d_out, int out_size, void* d_ws,
                              size_t ws_size, hipStream_t stream) {
  const float* feat  = (const float*)d_in[0];
  const float* props = (const float*)d_in[1];
  const float* W1    = (const float*)d_in[2];
  const float* b1    = (const float*)d_in[3];
  const float* W2    = (const float*)d_in[4];
  const float* b2    = (const float*)d_in[5];
  const float* Wcls  = (const float*)d_in[6];
  const float* bcls  = (const float*)d_in[7];
  const float* Wreg  = (const float*)d_in[8];
  const float* breg  = (const float*)d_in[9];
  float* out = (float*)d_out;

  char* wp = (char*)d_ws;
  unsigned short* pooled = (unsigned short*)wp; wp += (size_t)NROI * DIN * 2;
  unsigned short* W1T    = (unsigned short*)wp; wp += (size_t)OUT1 * DIN * 2;
  unsigned short* W2T    = (unsigned short*)wp; wp += (size_t)OUT1 * OUT1 * 2;
  unsigned short* x1     = (unsigned short*)wp; wp += (size_t)NROI * OUT1 * 2;
  float*          x2     = (float*)wp;          wp += (size_t)NROI * OUT1 * 4;
  float*          part   = (float*)wp;          wp += (size_t)4 * NROI * OUT1 * 4;
  unsigned short* fhwc   = (unsigned short*)wp;

  size_t need_min  = (size_t)(wp - (char*)d_ws);
  size_t need_full = need_min + (size_t)BB * CC * HH * WW * 2;

  if (ws_size >= need_full) {
    transpose_to_hwc_bf16<<<dim3(HH * WW / 64, CC / 64, BB), 256, 0, stream>>>(
        feat, fhwc);
    roi_align_hwc<<<NROI, 256, 0, stream>>>(fhwc, props, pooled);
  } else {
    roi_align_nchw<<<NROI, 256, 0, stream>>>(feat, props, pooled);
  }

  cvt_w<true><<<dim3(DIN / 64, OUT1 / 64), 256, 0, stream>>>(W1, W1T, OUT1, DIN);
  cvt_w<false><<<dim3(OUT1 / 64, OUT1 / 64), 256, 0, stream>>>(W2, W2T, OUT1, OUT1);

  gemm_mfma_128<<<dim3(8, 8, 4), 256, 0, stream>>>(pooled, W1T, part, DIN,
                                                   DIN / 4);
  reduce_relu_bf16<<<1024, 256, 0, stream>>>(part, b1, x1);
  gemm_mfma_64_fused<<<dim3(16, 16), 256, 0, stream>>>(x1, W2T, b2, x2, OUT1);
  head_kernel<<<NROI, 256, 0, stream>>>(x2, Wcls, bcls, Wreg, breg, props, out);
}

// Round 3
// 388.671 us; speedup vs baseline: 3.2256x; 1.0860x over previous
//
#include <hip/hip_runtime.h>
#include <math.h>
#include <stdint.h>

#define BB 2
#define NN 512
#define CC 256
#define HH 256
#define WW 256
#define DIN 12544    // C * 7 * 7
#define OUT1 1024
#define NCLS 11      // NUM_CLASSES + 1
#define NROI 1024    // B * N
#define SK1 8        // split-K for FC1 (must divide 392 k-iters' 12544/32)
#define SK2 2        // split-K for FC2

typedef short bf16x8 __attribute__((ext_vector_type(8)));
typedef float f32x4 __attribute__((ext_vector_type(4)));

__device__ inline unsigned short f2bf(float f) {
  unsigned int u = __float_as_uint(f);
  u += 0x7FFF + ((u >> 16) & 1);  // round-to-nearest-even
  return (unsigned short)(u >> 16);
}
__device__ inline float bf2f(unsigned short h) {
  return __uint_as_float(((unsigned int)h) << 16);
}
__device__ inline float4 ld_bf4(const unsigned short* p) {
  ushort4 r = *(const ushort4*)p;
  return make_float4(bf2f(r.x), bf2f(r.y), bf2f(r.z), bf2f(r.w));
}

// async global->LDS, 16B per lane; lds ptr must be wave-uniform base + lane*16
__device__ inline void gll16(const void* g, void* l) {
  __builtin_amdgcn_global_load_lds(
      reinterpret_cast<const __attribute__((address_space(1))) void*>(
          reinterpret_cast<uintptr_t>(g)),
      reinterpret_cast<__attribute__((address_space(3))) void*>(
          (unsigned int)reinterpret_cast<uintptr_t>(l)),
      16, 0, 0);
}

// ---------------------------------------------------------------------------
// NCHW fp32 -> NHWC bf16. Tile 64hw x 64c via LDS.
// ---------------------------------------------------------------------------
__global__ __launch_bounds__(256) void transpose_to_hwc_bf16(
    const float* __restrict__ in, unsigned short* __restrict__ out) {
  __shared__ float tile[64][65];
  int b = blockIdx.z;
  int hw0 = blockIdx.x * 64;
  int c0 = blockIdx.y * 64;
  int tid = threadIdx.x;
  int hi = tid >> 4, lo = tid & 15;
#pragma unroll
  for (int pass = 0; pass < 4; ++pass) {
    int cl = hi + pass * 16;
    float4 v = *(const float4*)(in + ((size_t)b * CC + c0 + cl) * (HH * WW) +
                                hw0 + lo * 4);
    tile[lo * 4 + 0][cl] = v.x;
    tile[lo * 4 + 1][cl] = v.y;
    tile[lo * 4 + 2][cl] = v.z;
    tile[lo * 4 + 3][cl] = v.w;
  }
  __syncthreads();
#pragma unroll
  for (int pass = 0; pass < 4; ++pass) {
    int hwl = hi + pass * 16;
    int cc = lo * 4;
    ushort4 o;
    o.x = f2bf(tile[hwl][cc + 0]);
    o.y = f2bf(tile[hwl][cc + 1]);
    o.z = f2bf(tile[hwl][cc + 2]);
    o.w = f2bf(tile[hwl][cc + 3]);
    *(ushort4*)(out + ((size_t)b * (HH * WW) + hw0 + hwl) * CC + c0 + cc) = o;
  }
}

// ---------------------------------------------------------------------------
__device__ inline void bilin(float gy, float gx, int& y0, int& x0, int& y1,
                             int& x1, float& w00, float& w01, float& w10,
                             float& w11) {
  float valid = (gy > -1.f && gy < 256.f && gx > -1.f && gx < 256.f) ? 0.25f : 0.f;
  float y = fminf(fmaxf(gy, 0.f), 255.f);
  float x = fminf(fmaxf(gx, 0.f), 255.f);
  float yf = floorf(y), xf = floorf(x);
  y0 = (int)yf; x0 = (int)xf;
  y1 = min(y0 + 1, 255); x1 = min(x0 + 1, 255);
  float ly = y - yf, lx = x - xf, hy = 1.f - ly, hx = 1.f - lx;
  w00 = hy * hx * valid; w01 = hy * lx * valid;
  w10 = ly * hx * valid; w11 = ly * lx * valid;
}

// ---------------------------------------------------------------------------
// ROI align rotated from NHWC bf16. pooled (bf16) layout [roi][bin*256 + c].
// ---------------------------------------------------------------------------
__global__ __launch_bounds__(256) void roi_align_hwc(
    const unsigned short* __restrict__ fhwc, const float* __restrict__ props,
    unsigned short* __restrict__ pooled) {
  int roi = blockIdx.x;
  int b = roi >> 9;
  const float* p = props + (size_t)roi * 5;
  float cx = p[0], cy = p[1], w = p[2], h = p[3], th = p[4];
  float sn = sinf(th), cs = cosf(th);
  int wave = threadIdx.x >> 6, lane = threadIdx.x & 63;
  int c4 = lane * 4;
  const unsigned short* fb = fhwc + (size_t)b * HH * WW * CC;
  unsigned short* outp = pooled + (size_t)roi * DIN;

  for (int bin = wave; bin < 49; bin += 4) {
    int py = bin / 7, px = bin - py * 7;
    float a0 = 0.f, a1 = 0.f, a2 = 0.f, a3 = 0.f;
#pragma unroll
    for (int sy = 0; sy < 2; ++sy) {
#pragma unroll
      for (int sx = 0; sx < 2; ++sx) {
        float ys = -0.5f * h + (h / 7.0f) * ((float)py + ((float)sy + 0.5f) * 0.5f);
        float xs = -0.5f * w + (w / 7.0f) * ((float)px + ((float)sx + 0.5f) * 0.5f);
        float gx = cx + xs * cs - ys * sn;
        float gy = cy + xs * sn + ys * cs;
        int y0, x0, y1, x1; float w00, w01, w10, w11;
        bilin(gy, gx, y0, x0, y1, x1, w00, w01, w10, w11);
        float4 v00 = ld_bf4(fb + ((size_t)(y0 * WW + x0)) * CC + c4);
        float4 v01 = ld_bf4(fb + ((size_t)(y0 * WW + x1)) * CC + c4);
        float4 v10 = ld_bf4(fb + ((size_t)(y1 * WW + x0)) * CC + c4);
        float4 v11 = ld_bf4(fb + ((size_t)(y1 * WW + x1)) * CC + c4);
        a0 += w00 * v00.x + w01 * v01.x + w10 * v10.x + w11 * v11.x;
        a1 += w00 * v00.y + w01 * v01.y + w10 * v10.y + w11 * v11.y;
        a2 += w00 * v00.z + w01 * v01.z + w10 * v10.z + w11 * v11.z;
        a3 += w00 * v00.w + w01 * v01.w + w10 * v10.w + w11 * v11.w;
      }
    }
    ushort4 o;
    o.x = f2bf(a0); o.y = f2bf(a1); o.z = f2bf(a2); o.w = f2bf(a3);
    *(ushort4*)(outp + bin * 256 + c4) = o;
  }
}

// Fallback: direct NCHW gather (small-ws path)
__global__ __launch_bounds__(256) void roi_align_nchw(
    const float* __restrict__ feat, const float* __restrict__ props,
    unsigned short* __restrict__ pooled) {
  int roi = blockIdx.x;
  int b = roi >> 9;
  int c = threadIdx.x;
  const float* p = props + (size_t)roi * 5;
  float cx = p[0], cy = p[1], w = p[2], h = p[3], th = p[4];
  float sn = sinf(th), cs = cosf(th);
  const float* fb = feat + ((size_t)b * CC + c) * (HH * WW);
  unsigned short* outp = pooled + (size_t)roi * DIN;
  for (int bin = 0; bin < 49; ++bin) {
    int py = bin / 7, px = bin - py * 7;
    float acc = 0.f;
#pragma unroll
    for (int sy = 0; sy < 2; ++sy) {
#pragma unroll
      for (int sx = 0; sx < 2; ++sx) {
        float ys = -0.5f * h + (h / 7.0f) * ((float)py + ((float)sy + 0.5f) * 0.5f);
        float xs = -0.5f * w + (w / 7.0f) * ((float)px + ((float)sx + 0.5f) * 0.5f);
        float gx = cx + xs * cs - ys * sn;
        float gy = cy + xs * sn + ys * cs;
        int y0, x0, y1, x1; float w00, w01, w10, w11;
        bilin(gy, gx, y0, x0, y1, x1, w00, w01, w10, w11);
        acc += w00 * fb[(size_t)y0 * WW + x0] + w01 * fb[(size_t)y0 * WW + x1] +
               w10 * fb[(size_t)y1 * WW + x0] + w11 * fb[(size_t)y1 * WW + x1];
      }
    }
    outp[bin * 256 + c] = f2bf(acc);
  }
}

// ---------------------------------------------------------------------------
// Weight convert: out[n][k'] = bf16(in[perm(k')][n]); perm(k')=(k'&255)*49+(k'>>8)
// ---------------------------------------------------------------------------
template <bool PERM>
__global__ __launch_bounds__(256) void cvt_w(const float* __restrict__ in,
                                             unsigned short* __restrict__ out,
                                             int N, int Kout) {
  __shared__ float tile[64][65];
  int k0 = blockIdx.x * 64, n0 = blockIdx.y * 64;
  int tid = threadIdx.x;
  int hi = tid >> 4, lo = tid & 15;
#pragma unroll
  for (int pass = 0; pass < 4; ++pass) {
    int ki = hi + pass * 16;
    int k = k0 + ki;
    int row = PERM ? ((k & 255) * 49 + (k >> 8)) : k;
    float4 v = *(const float4*)(in + (size_t)row * N + n0 + lo * 4);
    tile[ki][lo * 4 + 0] = v.x;
    tile[ki][lo * 4 + 1] = v.y;
    tile[ki][lo * 4 + 2] = v.z;
    tile[ki][lo * 4 + 3] = v.w;
  }
  __syncthreads();
#pragma unroll
  for (int pass = 0; pass < 4; ++pass) {
    int nl = hi + pass * 16;
    int kq = lo * 4;
    ushort4 o;
    o.x = f2bf(tile[kq + 0][nl]);
    o.y = f2bf(tile[kq + 1][nl]);
    o.z = f2bf(tile[kq + 2][nl]);
    o.w = f2bf(tile[kq + 3][nl]);
    *(ushort4*)(out + (size_t)(n0 + nl) * Kout + k0 + kq) = o;
  }
}

// ---------------------------------------------------------------------------
// MFMA GEMM, 128x128 tile, BK=32, split-K partials (fp32, no bias).
// A [M][K] bf16 row-major; Bw [N][K] bf16 row-major.
// ---------------------------------------------------------------------------
__global__ __launch_bounds__(256) void gemm_mfma_128(
    const unsigned short* __restrict__ A, const unsigned short* __restrict__ Bw,
    float* __restrict__ part, int K, int Ks) {
  __shared__ short As[128 * 32];
  __shared__ short Bs[128 * 32];
  int tid = threadIdx.x;
  int w = tid >> 6, lane = tid & 63;
  int quad = lane >> 4, l16 = lane & 15;
  int m0 = blockIdx.y * 128, n0 = blockIdx.x * 128;
  int bz = blockIdx.z;
  int wm = w >> 1, wn = w & 1;

  const char* pA = (const char*)A +
      ((size_t)(m0 + 32 * w + (lane >> 2)) * K + (size_t)bz * Ks) * 2 +
      (lane & 3) * 16;
  const char* pB = (const char*)Bw +
      ((size_t)(n0 + 32 * w + (lane >> 2)) * K + (size_t)bz * Ks) * 2 +
      (lane & 3) * 16;
  short* la = &As[w * 1024];
  short* lb = &Bs[w * 1024];
  const size_t rstep = (size_t)K * 2 * 16;  // +16 rows

  f32x4 acc[4][4] = {};
  int aoff[4], boff[4];
#pragma unroll
  for (int t = 0; t < 4; ++t) {
    aoff[t] = (wm * 64 + t * 16 + l16) * 32 + quad * 8;
    boff[t] = (wn * 64 + t * 16 + l16) * 32 + quad * 8;
  }

  for (int kk = 0; kk < Ks; kk += 32) {
    __syncthreads();  // prior reads done before LDS overwrite
    gll16(pA, la);
    gll16(pA + rstep, la + 512);
    gll16(pB, lb);
    gll16(pB + rstep, lb + 512);
    pA += 64; pB += 64;
    __syncthreads();  // vmcnt(0) drained -> LDS valid
    bf16x8 af[4], bfr[4];
#pragma unroll
    for (int t = 0; t < 4; ++t) af[t] = *(const bf16x8*)&As[aoff[t]];
#pragma unroll
    for (int t = 0; t < 4; ++t) bfr[t] = *(const bf16x8*)&Bs[boff[t]];
#pragma unroll
    for (int mt = 0; mt < 4; ++mt)
#pragma unroll
      for (int nt = 0; nt < 4; ++nt)
        acc[mt][nt] = __builtin_amdgcn_mfma_f32_16x16x32_bf16(
            af[mt], bfr[nt], acc[mt][nt], 0, 0, 0);
  }

  float* pp = part + (size_t)bz * (OUT1 * NROI);
#pragma unroll
  for (int mt = 0; mt < 4; ++mt)
#pragma unroll
    for (int nt = 0; nt < 4; ++nt) {
      int col = n0 + wn * 64 + nt * 16 + l16;
#pragma unroll
      for (int r = 0; r < 4; ++r) {
        int row = m0 + wm * 64 + mt * 16 + quad * 4 + r;
        pp[(size_t)row * OUT1 + col] = acc[mt][nt][r];
      }
    }
}

// split-K reduce + bias + relu -> bf16 (SK1 partials)
__global__ __launch_bounds__(256) void reduce_relu_bf16(
    const float* __restrict__ part, const float* __restrict__ bias,
    unsigned short* __restrict__ out) {
  int i = blockIdx.x * 256 + threadIdx.x;  // float4 index
  int base = i * 4;
  int col = base & (OUT1 - 1);
  const float4* p = (const float4*)part;
  float4 s = p[i];
#pragma unroll
  for (int z = 1; z < SK1; ++z) {
    float4 t = p[i + (size_t)z * (NROI * OUT1 / 4)];
    s.x += t.x; s.y += t.y; s.z += t.z; s.w += t.w;
  }
  float4 bv = *(const float4*)(bias + col);
  ushort4 o;
  o.x = f2bf(fmaxf(s.x + bv.x, 0.f));
  o.y = f2bf(fmaxf(s.y + bv.y, 0.f));
  o.z = f2bf(fmaxf(s.z + bv.z, 0.f));
  o.w = f2bf(fmaxf(s.w + bv.w, 0.f));
  *(ushort4*)(out + base) = o;
}

// ---------------------------------------------------------------------------
// MFMA GEMM, 64x64 tile, BK=64, split-K partials fp32. A[M][K], Bw[N][K].
// ---------------------------------------------------------------------------
__global__ __launch_bounds__(256) void gemm_mfma_64_part(
    const unsigned short* __restrict__ A, const unsigned short* __restrict__ Bw,
    float* __restrict__ part, int K, int Ks) {
  __shared__ short As[64 * 64];
  __shared__ short Bs[64 * 64];
  int tid = threadIdx.x;
  int w = tid >> 6, lane = tid & 63;
  int quad = lane >> 4, l16 = lane & 15;
  int m0 = blockIdx.y * 64, n0 = blockIdx.x * 64;
  int bz = blockIdx.z;
  int wm = w >> 1, wn = w & 1;

  const char* pA = (const char*)A +
      ((size_t)(m0 + 16 * w + (lane >> 3)) * K + (size_t)bz * Ks) * 2 +
      (lane & 7) * 16;
  const char* pB = (const char*)Bw +
      ((size_t)(n0 + 16 * w + (lane >> 3)) * K + (size_t)bz * Ks) * 2 +
      (lane & 7) * 16;
  short* la = &As[w * 1024];
  short* lb = &Bs[w * 1024];
  const size_t rstep = (size_t)K * 2 * 8;  // +8 rows

  f32x4 acc[2][2] = {};
  int aoff[2], boff[2];
#pragma unroll
  for (int t = 0; t < 2; ++t) {
    aoff[t] = (wm * 32 + t * 16 + l16) * 64 + quad * 8;
    boff[t] = (wn * 32 + t * 16 + l16) * 64 + quad * 8;
  }

  for (int kk = 0; kk < Ks; kk += 64) {
    __syncthreads();
    gll16(pA, la);
    gll16(pA + rstep, la + 512);
    gll16(pB, lb);
    gll16(pB + rstep, lb + 512);
    pA += 128; pB += 128;
    __syncthreads();
#pragma unroll
    for (int ks = 0; ks < 2; ++ks) {
      bf16x8 af[2], bfr[2];
#pragma unroll
      for (int t = 0; t < 2; ++t) af[t] = *(const bf16x8*)&As[aoff[t] + ks * 32];
#pragma unroll
      for (int t = 0; t < 2; ++t) bfr[t] = *(const bf16x8*)&Bs[boff[t] + ks * 32];
#pragma unroll
      for (int mt = 0; mt < 2; ++mt)
#pragma unroll
        for (int nt = 0; nt < 2; ++nt)
          acc[mt][nt] = __builtin_amdgcn_mfma_f32_16x16x32_bf16(
              af[mt], bfr[nt], acc[mt][nt], 0, 0, 0);
    }
  }
  float* pp = part + (size_t)bz * (OUT1 * NROI);
#pragma unroll
  for (int mt = 0; mt < 2; ++mt)
#pragma unroll
    for (int nt = 0; nt < 2; ++nt) {
      int col = n0 + wn * 32 + nt * 16 + l16;
#pragma unroll
      for (int r = 0; r < 4; ++r) {
        int row = m0 + wm * 32 + mt * 16 + quad * 4 + r;
        pp[(size_t)row * OUT1 + col] = acc[mt][nt][r];
      }
    }
}

// ---------------------------------------------------------------------------
// Head: x2 = relu(p0+p1+b2) on the fly; cls/reg GEMV + box decode.
// ---------------------------------------------------------------------------
__global__ __launch_bounds__(256) void head_kernel(
    const float* __restrict__ P0, const float* __restrict__ P1,
    const float* __restrict__ b2, const float* __restrict__ Wcls,
    const float* __restrict__ bcls, const float* __restrict__ Wreg,
    const float* __restrict__ breg, const float* __restrict__ props,
    float* __restrict__ out) {
  __shared__ float xrow[1024];
  __shared__ float partial[16][17];
  __shared__ float res[16];
  int row = blockIdx.x;
  int tid = threadIdx.x;
  {
    size_t off = (size_t)row * 1024 + tid * 4;
    float4 a = *(const float4*)(P0 + off);
    float4 b = *(const float4*)(P1 + off);
    float4 bv = *(const float4*)(b2 + tid * 4);
    xrow[tid * 4 + 0] = fmaxf(a.x + b.x + bv.x, 0.f);
    xrow[tid * 4 + 1] = fmaxf(a.y + b.y + bv.y, 0.f);
    xrow[tid * 4 + 2] = fmaxf(a.z + b.z + bv.z, 0.f);
    xrow[tid * 4 + 3] = fmaxf(a.w + b.w + bv.w, 0.f);
  }
  __syncthreads();
  int col = tid & 15, slice = tid >> 4;
  float s = 0.f;
  if (col < NCLS) {
    for (int k = slice * 64; k < slice * 64 + 64; ++k)
      s += xrow[k] * Wcls[(size_t)k * NCLS + col];
  } else {
    int rc = col - NCLS;
    for (int k = slice * 64; k < slice * 64 + 64; ++k)
      s += xrow[k] * Wreg[(size_t)k * 5 + rc];
  }
  partial[slice][col] = s;
  __syncthreads();
  if (tid < 16) {
    float t = 0.f;
    for (int sl = 0; sl < 16; ++sl) t += partial[sl][tid];
    t += (tid < NCLS) ? bcls[tid] : breg[tid - NCLS];
    res[tid] = t;
  }
  __syncthreads();
  if (tid < NCLS) out[5120 + (size_t)row * NCLS + tid] = res[tid];
  if (tid == 0) {
    const float* p = props + (size_t)row * 5;
    float p0 = p[0] * 4.f, p1 = p[1] * 4.f, p2 = p[2] * 4.f, p3 = p[3] * 4.f,
          p4 = p[4];
    float r0 = res[11], r1 = res[12], r2 = res[13], r3 = res[14], r4 = res[15];
    const float V = 4.135166556742356f;  // |log(16/1000)|
    float bx = p2 * r0 + p0;
    float by = p3 * r1 + p1;
    float bw = p2 * expf(fminf(fmaxf(r2, -V), V));
    float bh = p3 * expf(fminf(fmaxf(r3, -V), V));
    const float PI = 3.14159265358979323846f;
    float a = p4 + r4;
    float m = fmodf(a + PI * 0.5f, PI);
    if (m < 0.f) m += PI;
    float ba = m - PI * 0.5f;
    float* bo = out + (size_t)row * 5;
    bo[0] = bx; bo[1] = by; bo[2] = bw; bo[3] = bh; bo[4] = ba;
  }
}

// ---------------------------------------------------------------------------
extern "C" void kernel_launch(void* const* d_in, const int* in_sizes, int n_in,
                              void* d_out, int out_size, void* d_ws,
                              size_t ws_size, hipStream_t stream) {
  const float* feat  = (const float*)d_in[0];
  const float* props = (const float*)d_in[1];
  const float* W1    = (const float*)d_in[2];
  const float* b1    = (const float*)d_in[3];
  const float* W2    = (const float*)d_in[4];
  const float* b2    = (const float*)d_in[5];
  const float* Wcls  = (const float*)d_in[6];
  const float* bcls  = (const float*)d_in[7];
  const float* Wreg  = (const float*)d_in[8];
  const float* breg  = (const float*)d_in[9];
  float* out = (float*)d_out;

  char* wp = (char*)d_ws;
  unsigned short* pooled = (unsigned short*)wp; wp += (size_t)NROI * DIN * 2;
  unsigned short* W1T    = (unsigned short*)wp; wp += (size_t)OUT1 * DIN * 2;
  unsigned short* W2T    = (unsigned short*)wp; wp += (size_t)OUT1 * OUT1 * 2;
  unsigned short* x1     = (unsigned short*)wp; wp += (size_t)NROI * OUT1 * 2;
  float*          part1  = (float*)wp;          wp += (size_t)SK1 * NROI * OUT1 * 4;
  float*          part2  = (float*)wp;          wp += (size_t)SK2 * NROI * OUT1 * 4;
  unsigned short* fhwc   = (unsigned short*)wp;

  size_t need_min  = (size_t)(wp - (char*)d_ws);
  size_t need_full = need_min + (size_t)BB * CC * HH * WW * 2;

  if (ws_size >= need_full) {
    transpose_to_hwc_bf16<<<dim3(HH * WW / 64, CC / 64, BB), 256, 0, stream>>>(
        feat, fhwc);
    roi_align_hwc<<<NROI, 256, 0, stream>>>(fhwc, props, pooled);
  } else {
    roi_align_nchw<<<NROI, 256, 0, stream>>>(feat, props, pooled);
  }

  cvt_w<true><<<dim3(DIN / 64, OUT1 / 64), 256, 0, stream>>>(W1, W1T, OUT1, DIN);
  cvt_w<false><<<dim3(OUT1 / 64, OUT1 / 64), 256, 0, stream>>>(W2, W2T, OUT1, OUT1);

  gemm_mfma_128<<<dim3(8, 8, SK1), 256, 0, stream>>>(pooled, W1T, part1, DIN,
                                                     DIN / SK1);
  reduce_relu_bf16<<<NROI * OUT1 / 1024, 256, 0, stream>>>(part1, b1, x1);
  gemm_mfma_64_part<<<dim3(16, 16, SK2), 256, 0, stream>>>(x1, W2T, part2, OUT1,
                                                           OUT1 / SK2);
  head_kernel<<<NROI, 256, 0, stream>>>(part2, part2 + (size_t)NROI * OUT1, b2,
                                        Wcls, bcls, Wreg, breg, props, out);
}